// Round 4
// baseline (1040.414 us; speedup 1.0000x reference)
//
#include <hip/hip_runtime.h>

typedef unsigned short u16;
typedef u16   u16x8  __attribute__((ext_vector_type(8)));
typedef short short8 __attribute__((ext_vector_type(8)));
typedef float floatx4 __attribute__((ext_vector_type(4)));
typedef float f4     __attribute__((ext_vector_type(4)));

#define BB 8
#define NN 4096
#define CC 384

__device__ __forceinline__ u16 f2bf(float f){
  unsigned u = __float_as_uint(f);
  u += 0x7FFFu + ((u >> 16) & 1u);   // round-to-nearest-even
  return (u16)(u >> 16);
}
__device__ __forceinline__ float bf2f(u16 u){ return __uint_as_float(((unsigned)u) << 16); }

// ---------------- Kernel 1: depthwise conv 3x3 + LayerNorm + GELU(erf) + residual -> xa (f32) ----
__global__ __launch_bounds__(384) void k_conv_ln_gelu(
    const float* __restrict__ x, const float* __restrict__ w_sr, const float* __restrict__ b_sr,
    const float* __restrict__ ln_g, const float* __restrict__ ln_b, float* __restrict__ xa)
{
  const int pix = blockIdx.x;            // b*4096 + n
  const int b = pix >> 12, n = pix & 4095;
  const int hh = n >> 6, ww = n & 63;
  const int c = threadIdx.x;

  float wgt[9];
#pragma unroll
  for (int i = 0; i < 9; i++) wgt[i] = w_sr[c * 9 + i];

  float acc = b_sr[c];
#pragma unroll
  for (int kh = 0; kh < 3; kh++) {
    int y = hh + kh - 1;
    if ((unsigned)y >= 64u) continue;
#pragma unroll
    for (int kw = 0; kw < 3; kw++) {
      int xx = ww + kw - 1;
      if ((unsigned)xx >= 64u) continue;
      acc += x[(((b << 12) + (y << 6) + xx) * CC) + c] * wgt[kh * 3 + kw];
    }
  }

  float s1 = acc, s2 = acc * acc;
#pragma unroll
  for (int o = 32; o > 0; o >>= 1) { s1 += __shfl_down(s1, o); s2 += __shfl_down(s2, o); }
  __shared__ float ls1[6], ls2[6], mb[2];
  const int wid = threadIdx.x >> 6, lane = threadIdx.x & 63;
  if (lane == 0) { ls1[wid] = s1; ls2[wid] = s2; }
  __syncthreads();
  if (threadIdx.x == 0) {
    float a = 0.f, q = 0.f;
#pragma unroll
    for (int i = 0; i < 6; i++) { a += ls1[i]; q += ls2[i]; }
    float mean = a * (1.0f / CC);
    float var  = q * (1.0f / CC) - mean * mean;
    mb[0] = mean; mb[1] = rsqrtf(var + 1e-5f);
  }
  __syncthreads();
  float xn = (acc - mb[0]) * mb[1] * ln_g[c] + ln_b[c];
  float g  = 0.5f * xn * (1.0f + erff(xn * 0.70710678118654752f));
  xa[pix * CC + c] = x[pix * CC + c] + g;
}

// ---------------- Kernel 2: fused k|v GEMM + k-softmax + ctx accumulation ------------------------
// grid (128 rowtiles of 256, 8 heads), block 256. ctx[bh,48,48] += sum_n ksm[n,d]*v[n,e]
__global__ __launch_bounds__(256) void k_kvctx(
    const float* __restrict__ xa, const float* __restrict__ wqkv, float* __restrict__ ctx)
{
  const int rt = blockIdx.x, h = blockIdx.y;
  const int n0 = rt << 8;
  const int bh = ((rt >> 4) << 3) + h;
  const int tid = threadIdx.x;
  const int wv = tid >> 6, lane = tid & 63, l15 = lane & 15, quad = lane >> 4;

  __shared__ __attribute__((aligned(16))) char smem[57344];
  u16 (*lA)[72] = (u16(*)[72])smem;            // 256 x 72  (xa rows, k-chunk) bf16
  u16 (*lW)[72] = (u16(*)[72])(smem + 36864);  // 96  x 72  (w cols transposed) bf16
  u16 (*lk)[56] = (u16(*)[56])smem;            // 256 x 56
  u16 (*lv)[56] = (u16(*)[56])(smem + 28672);  // 256 x 56

  floatx4 acc[24];
  const floatx4 z = {0.f, 0.f, 0.f, 0.f};
#pragma unroll
  for (int i = 0; i < 24; i++) acc[i] = z;

  for (int k0 = 0; k0 < 384; k0 += 64) {
    __syncthreads();
    // stage A: 256 rows x 64 k (f32 -> bf16)
#pragma unroll
    for (int i = 0; i < 16; i++) {
      int idx = tid + (i << 8);               // 0..4095
      int r = idx >> 4, c4 = (idx & 15) << 2;
      f4 v = *(const f4*)(xa + (size_t)(n0 + r) * 384 + k0 + c4);
#pragma unroll
      for (int j = 0; j < 4; j++) lA[r][c4 + j] = f2bf(v[j]);
    }
    // stage W: 64 k-rows x 96 cols (k|v of head h), transposed (f32 -> bf16)
#pragma unroll
    for (int i = 0; i < 6; i++) {
      int idx = tid + (i << 8);               // 0..1535
      int r = idx / 24, g = idx % 24;
      int colbase = (g < 12) ? (384 + h * 48 + (g << 2)) : (768 + h * 48 + ((g - 12) << 2));
      f4 v = *(const f4*)(wqkv + (size_t)(k0 + r) * 1152 + colbase);
      int cb = g << 2;
#pragma unroll
      for (int j = 0; j < 4; j++) lW[cb + j][r] = f2bf(v[j]);
    }
    __syncthreads();
#pragma unroll
    for (int rt4 = 0; rt4 < 4; rt4++) {
      int m = (wv << 6) + (rt4 << 4) + l15;
#pragma unroll
      for (int kk = 0; kk < 2; kk++) {
        short8 af = *(const short8*)&lA[m][(kk << 5) + (quad << 3)];
#pragma unroll
        for (int ct = 0; ct < 6; ct++) {
          short8 bf = *(const short8*)&lW[(ct << 4) + l15][(kk << 5) + (quad << 3)];
          acc[rt4 * 6 + ct] = __builtin_amdgcn_mfma_f32_16x16x32_bf16(af, bf, acc[rt4 * 6 + ct], 0, 0, 0);
        }
      }
    }
  }
  __syncthreads();   // done reading lA/lW; smem reused as lk/lv
#pragma unroll
  for (int rt4 = 0; rt4 < 4; rt4++) {
#pragma unroll
    for (int ct = 0; ct < 6; ct++) {
      int col = (ct << 4) + l15;
#pragma unroll
      for (int rr = 0; rr < 4; rr++) {
        int row = (wv << 6) + (rt4 << 4) + (quad << 2) + rr;
        u16 val = f2bf(acc[rt4 * 6 + ct][rr]);
        if (col < 48) lk[row][col] = val; else lv[row][col - 48] = val;
      }
    }
  }
  __syncthreads();
  // softmax over each k row (thread tid owns row tid)
  {
    float v[48];
#pragma unroll
    for (int i = 0; i < 48; i++) v[i] = bf2f(lk[tid][i]);
    float m = v[0];
#pragma unroll
    for (int i = 1; i < 48; i++) m = fmaxf(m, v[i]);
    float s = 0.f;
#pragma unroll
    for (int i = 0; i < 48; i++) { v[i] = expf(v[i] - m); s += v[i]; }
    float inv = 1.0f / s;
#pragma unroll
    for (int i = 0; i < 48; i++) lk[tid][i] = f2bf(v[i] * inv);
  }
  __syncthreads();
  // ctx accumulation: each thread owns 9 (d,e) cells
  float a9[9]; int dd[9], ee[9];
#pragma unroll
  for (int i = 0; i < 9; i++) {
    int cell = tid + (i << 8);
    dd[i] = cell / 48; ee[i] = cell - dd[i] * 48; a9[i] = 0.f;
  }
  for (int r = 0; r < 256; r++) {
#pragma unroll
    for (int i = 0; i < 9; i++) a9[i] += bf2f(lk[r][dd[i]]) * bf2f(lv[r][ee[i]]);
  }
#pragma unroll
  for (int i = 0; i < 9; i++) atomicAdd(&ctx[(size_t)bh * 2304 + tid + (i << 8)], a9[i]);
}

// ---------------- Kernel 3: q GEMM tile + column sums of exp(q) -> S[b*384+col] -----------------
__global__ __launch_bounds__(256) void k_qsumk(
    const float* __restrict__ xa, const float* __restrict__ wqkv, float* __restrict__ S)
{
  const int bm = blockIdx.x;           // 512 row-tiles of 64
  const int b = bm >> 6;
  const int tid = threadIdx.x;
  const int wv = tid >> 6, lane = tid & 63, l15 = lane & 15, quad = lane >> 4;
  __shared__ __attribute__((aligned(16))) u16 lA[64][72];
  __shared__ __attribute__((aligned(16))) u16 lB[64][72];

  floatx4 acc[24];
  const floatx4 z = {0.f, 0.f, 0.f, 0.f};
#pragma unroll
  for (int i = 0; i < 24; i++) acc[i] = z;

  for (int k0 = 0; k0 < 384; k0 += 64) {
    __syncthreads();
#pragma unroll
    for (int i = 0; i < 4; i++) {
      int idx = tid + (i << 8);               // 0..1023
      int r = idx >> 4, c4 = (idx & 15) << 2;
      f4 v = *(const f4*)(xa + (size_t)((bm << 6) + r) * 384 + k0 + c4);
#pragma unroll
      for (int j = 0; j < 4; j++) lA[r][c4 + j] = f2bf(v[j]);
    }
    for (int ctg = 0; ctg < 6; ctg++) {
      __syncthreads();
#pragma unroll
      for (int i = 0; i < 4; i++) {
        int idx = tid + (i << 8);
        int r = idx >> 4, c4 = (idx & 15) << 2;    // r = k row, c4 = col offset
        f4 v = *(const f4*)(wqkv + (size_t)(k0 + r) * 1152 + (ctg << 6) + c4);
#pragma unroll
        for (int j = 0; j < 4; j++) lB[c4 + j][r] = f2bf(v[j]);
      }
      __syncthreads();
      int m = (wv << 4) + l15;
#pragma unroll
      for (int kk = 0; kk < 2; kk++) {
        short8 af = *(const short8*)&lA[m][(kk << 5) + (quad << 3)];
#pragma unroll
        for (int c4i = 0; c4i < 4; c4i++) {
          short8 bf = *(const short8*)&lB[(c4i << 4) + l15][(kk << 5) + (quad << 3)];
          acc[(ctg << 2) + c4i] = __builtin_amdgcn_mfma_f32_16x16x32_bf16(af, bf, acc[(ctg << 2) + c4i], 0, 0, 0);
        }
      }
    }
  }
#pragma unroll
  for (int t = 0; t < 24; t++) {
    float s = expf(acc[t][0]) + expf(acc[t][1]) + expf(acc[t][2]) + expf(acc[t][3]);
    s += __shfl_down(s, 32);
    s += __shfl_down(s, 16);
    if (lane < 16) atomicAdd(&S[b * 384 + (t << 4) + lane], s);
  }
}

// ---------------- Kernel 4: W2[b, h*48+d, c] = sum_e (ctx[bh,d,e]/S[..]) * wp[h*48+e, c] --------
__global__ __launch_bounds__(256) void k_w2(
    const float* __restrict__ ctx, const float* __restrict__ S,
    const float* __restrict__ wp, u16* __restrict__ W2)
{
  const int bh = blockIdx.x;   // 64
  const int b = bh >> 3, h = bh & 7;
  const int tid = threadIdx.x;
  __shared__ float rs[48];
  __shared__ float c2[48][48];
  if (tid < 48) rs[tid] = 1.0f / S[b * 384 + h * 48 + tid];
  __syncthreads();
#pragma unroll
  for (int i = 0; i < 9; i++) {
    int cell = tid + (i << 8);
    int d = cell / 48, e = cell - d * 48;
    c2[d][e] = ctx[(size_t)bh * 2304 + cell] * rs[d];
  }
  __syncthreads();
  for (int d = 0; d < 48; d++) {
#pragma unroll
    for (int c0 = 0; c0 < 384; c0 += 256) {
      int c = c0 + tid;
      if (c < 384) {
        float s = 0.f;
#pragma unroll
        for (int e = 0; e < 48; e++) s += c2[d][e] * wp[(size_t)(h * 48 + e) * 384 + c];
        W2[((size_t)b * 384 + h * 48 + d) * 384 + c] = f2bf(s);
      }
    }
  }
}

// ---------------- Kernel 5: out = exp(q_tile) @ W2_b + bias + x  (q recomputed in-block) --------
__global__ __launch_bounds__(256) void k_qproj(
    const float* __restrict__ xa, const float* __restrict__ wqkv, const u16* __restrict__ W2,
    const float* __restrict__ bias, const float* __restrict__ x, float* __restrict__ out)
{
  const int bm = blockIdx.x;           // 512 row-tiles of 64
  const int b = bm >> 6;
  const int tid = threadIdx.x;
  const int wv = tid >> 6, lane = tid & 63, l15 = lane & 15, quad = lane >> 4;
  __shared__ __attribute__((aligned(16))) u16 lA[64][72];
  __shared__ __attribute__((aligned(16))) u16 lB[64][72];
  __shared__ __attribute__((aligned(16))) u16 P[64][392];

  floatx4 acc[24];
  const floatx4 z = {0.f, 0.f, 0.f, 0.f};
#pragma unroll
  for (int i = 0; i < 24; i++) acc[i] = z;

  // phase 1: q = xa_rows @ wqkv[:, 0:384]
  for (int k0 = 0; k0 < 384; k0 += 64) {
    __syncthreads();
#pragma unroll
    for (int i = 0; i < 4; i++) {
      int idx = tid + (i << 8);
      int r = idx >> 4, c4 = (idx & 15) << 2;
      f4 v = *(const f4*)(xa + (size_t)((bm << 6) + r) * 384 + k0 + c4);
#pragma unroll
      for (int j = 0; j < 4; j++) lA[r][c4 + j] = f2bf(v[j]);
    }
    for (int ctg = 0; ctg < 6; ctg++) {
      __syncthreads();
#pragma unroll
      for (int i = 0; i < 4; i++) {
        int idx = tid + (i << 8);
        int r = idx >> 4, c4 = (idx & 15) << 2;
        f4 v = *(const f4*)(wqkv + (size_t)(k0 + r) * 1152 + (ctg << 6) + c4);
#pragma unroll
        for (int j = 0; j < 4; j++) lB[c4 + j][r] = f2bf(v[j]);
      }
      __syncthreads();
      int m = (wv << 4) + l15;
#pragma unroll
      for (int kk = 0; kk < 2; kk++) {
        short8 af = *(const short8*)&lA[m][(kk << 5) + (quad << 3)];
#pragma unroll
        for (int c4i = 0; c4i < 4; c4i++) {
          short8 bf = *(const short8*)&lB[(c4i << 4) + l15][(kk << 5) + (quad << 3)];
          acc[(ctg << 2) + c4i] = __builtin_amdgcn_mfma_f32_16x16x32_bf16(af, bf, acc[(ctg << 2) + c4i], 0, 0, 0);
        }
      }
    }
  }
  __syncthreads();
  // P = exp(q) in bf16
#pragma unroll
  for (int t = 0; t < 24; t++) {
    int col = (t << 4) + l15;
#pragma unroll
    for (int rr = 0; rr < 4; rr++) {
      int row = (wv << 4) + (quad << 2) + rr;
      P[row][col] = f2bf(expf(acc[t][rr]));
    }
  }
#pragma unroll
  for (int i = 0; i < 24; i++) acc[i] = z;
  __syncthreads();

  // phase 2: out_tile = P @ W2_b
  for (int k0 = 0; k0 < 384; k0 += 64) {
    for (int ctg = 0; ctg < 6; ctg++) {
      __syncthreads();
#pragma unroll
      for (int i = 0; i < 2; i++) {
        int idx = tid + (i << 8);
        int r = idx >> 3, c8 = (idx & 7) << 3;
        u16x8 v = *(const u16x8*)(W2 + ((size_t)b * 384 + k0 + r) * 384 + (ctg << 6) + c8);
#pragma unroll
        for (int j = 0; j < 8; j++) lB[c8 + j][r] = v[j];
      }
      __syncthreads();
      int m = (wv << 4) + l15;
#pragma unroll
      for (int kk = 0; kk < 2; kk++) {
        short8 af = *(const short8*)&P[m][k0 + (kk << 5) + (quad << 3)];
#pragma unroll
        for (int c4i = 0; c4i < 4; c4i++) {
          short8 bf = *(const short8*)&lB[(c4i << 4) + l15][(kk << 5) + (quad << 3)];
          acc[(ctg << 2) + c4i] = __builtin_amdgcn_mfma_f32_16x16x32_bf16(af, bf, acc[(ctg << 2) + c4i], 0, 0, 0);
        }
      }
    }
  }
  // epilogue: + bias + x, write out (own rows only -> in-place over xa is safe)
#pragma unroll
  for (int t = 0; t < 24; t++) {
    int col = (t << 4) + l15;
#pragma unroll
    for (int rr = 0; rr < 4; rr++) {
      int row = (bm << 6) + (wv << 4) + (quad << 2) + rr;
      float v = acc[t][rr] + bias[col] + x[(size_t)row * 384 + col];
      out[(size_t)row * 384 + col] = v;
    }
  }
}

extern "C" void kernel_launch(void* const* d_in, const int* in_sizes, int n_in,
                              void* d_out, int out_size, void* d_ws, size_t ws_size,
                              hipStream_t stream)
{
  const float* x      = (const float*)d_in[0];
  const float* w_sr   = (const float*)d_in[1];
  const float* b_sr   = (const float*)d_in[2];
  const float* ln_g   = (const float*)d_in[3];
  const float* ln_b   = (const float*)d_in[4];
  const float* w_qkv  = (const float*)d_in[5];
  const float* w_proj = (const float*)d_in[6];
  const float* b_proj = (const float*)d_in[7];
  float* out = (float*)d_out;

  // ws layout — total 2,961,408 bytes (~2.96 MB):
  //   [0,      12288)   S   [8][384] f32   (column sums of exp(q))
  //   [12288,  602112)  ctx [64][48][48] f32
  //   [602112, 2961408) W2  [8][384][384] bf16
  float* S   = (float*)d_ws;
  float* ctx = (float*)((char*)d_ws + 12288);
  u16*   W2  = (u16*)((char*)d_ws + 602112);
  float* xa  = out;   // conv result (f32) lives in d_out until k_qproj overwrites it row-locally

  hipMemsetAsync(d_ws, 0, 602112, stream);   // zero S + ctx

  k_conv_ln_gelu<<<BB * NN, CC, 0, stream>>>(x, w_sr, b_sr, ln_g, ln_b, xa);
  k_kvctx<<<dim3(128, 8), 256, 0, stream>>>(xa, w_qkv, ctx);
  k_qsumk<<<512, 256, 0, stream>>>(xa, w_qkv, S);
  k_w2<<<64, 256, 0, stream>>>(ctx, S, w_proj, W2);
  k_qproj<<<512, 256, 0, stream>>>(xa, w_qkv, W2, b_proj, x, out);
}

// Round 5
// 698.408 us; speedup vs baseline: 1.4897x; 1.4897x over previous
//
#include <hip/hip_runtime.h>

typedef unsigned short u16;
typedef u16   u16x8  __attribute__((ext_vector_type(8)));
typedef short short8 __attribute__((ext_vector_type(8)));
typedef float floatx4 __attribute__((ext_vector_type(4)));
typedef float f4     __attribute__((ext_vector_type(4)));

#define BB 8
#define NN 4096
#define CC 384

__device__ __forceinline__ u16 f2bf(float f){
  unsigned u = __float_as_uint(f);
  u += 0x7FFFu + ((u >> 16) & 1u);   // round-to-nearest-even
  return (u16)(u >> 16);
}
__device__ __forceinline__ float bf2f(u16 u){ return __uint_as_float(((unsigned)u) << 16); }

// ---------------- Kernel 1: depthwise conv 3x3 + LayerNorm + GELU(erf) + residual -> xa (f32) ----
__global__ __launch_bounds__(384) void k_conv_ln_gelu(
    const float* __restrict__ x, const float* __restrict__ w_sr, const float* __restrict__ b_sr,
    const float* __restrict__ ln_g, const float* __restrict__ ln_b, float* __restrict__ xa)
{
  const int pix = blockIdx.x;            // b*4096 + n
  const int b = pix >> 12, n = pix & 4095;
  const int hh = n >> 6, ww = n & 63;
  const int c = threadIdx.x;

  float wgt[9];
#pragma unroll
  for (int i = 0; i < 9; i++) wgt[i] = w_sr[c * 9 + i];

  float acc = b_sr[c];
#pragma unroll
  for (int kh = 0; kh < 3; kh++) {
    int y = hh + kh - 1;
    if ((unsigned)y >= 64u) continue;
#pragma unroll
    for (int kw = 0; kw < 3; kw++) {
      int xx = ww + kw - 1;
      if ((unsigned)xx >= 64u) continue;
      acc += x[(((b << 12) + (y << 6) + xx) * CC) + c] * wgt[kh * 3 + kw];
    }
  }

  float s1 = acc, s2 = acc * acc;
#pragma unroll
  for (int o = 32; o > 0; o >>= 1) { s1 += __shfl_down(s1, o); s2 += __shfl_down(s2, o); }
  __shared__ float ls1[6], ls2[6], mb[2];
  const int wid = threadIdx.x >> 6, lane = threadIdx.x & 63;
  if (lane == 0) { ls1[wid] = s1; ls2[wid] = s2; }
  __syncthreads();
  if (threadIdx.x == 0) {
    float a = 0.f, q = 0.f;
#pragma unroll
    for (int i = 0; i < 6; i++) { a += ls1[i]; q += ls2[i]; }
    float mean = a * (1.0f / CC);
    float var  = q * (1.0f / CC) - mean * mean;
    mb[0] = mean; mb[1] = rsqrtf(var + 1e-5f);
  }
  __syncthreads();
  float xn = (acc - mb[0]) * mb[1] * ln_g[c] + ln_b[c];
  float g  = 0.5f * xn * (1.0f + erff(xn * 0.70710678118654752f));
  xa[pix * CC + c] = x[pix * CC + c] + g;
}

// ---------------- Kernel 2: fused k|v GEMM + k-softmax + ctx accumulation ------------------------
// grid (128 rowtiles of 256, 8 heads), block 256. ctx[bh,48,48] += sum_n ksm[n,d]*v[n,e]
__global__ __launch_bounds__(256) void k_kvctx(
    const float* __restrict__ xa, const float* __restrict__ wqkv, float* __restrict__ ctx)
{
  const int rt = blockIdx.x, h = blockIdx.y;
  const int n0 = rt << 8;
  const int bh = ((rt >> 4) << 3) + h;
  const int tid = threadIdx.x;
  const int wv = tid >> 6, lane = tid & 63, l15 = lane & 15, quad = lane >> 4;

  __shared__ __attribute__((aligned(16))) char smem[57344];
  u16 (*lA)[72] = (u16(*)[72])smem;            // 256 x 72  (xa rows, k-chunk) bf16
  u16 (*lW)[72] = (u16(*)[72])(smem + 36864);  // 96  x 72  (w cols transposed) bf16
  u16 (*lk)[56] = (u16(*)[56])smem;            // 256 x 56
  u16 (*lv)[56] = (u16(*)[56])(smem + 28672);  // 256 x 56

  floatx4 acc[24];
  const floatx4 z = {0.f, 0.f, 0.f, 0.f};
#pragma unroll
  for (int i = 0; i < 24; i++) acc[i] = z;

  for (int k0 = 0; k0 < 384; k0 += 64) {
    __syncthreads();
    // stage A: 256 rows x 64 k (f32 -> bf16)
#pragma unroll
    for (int i = 0; i < 16; i++) {
      int idx = tid + (i << 8);               // 0..4095
      int r = idx >> 4, c4 = (idx & 15) << 2;
      f4 v = *(const f4*)(xa + (size_t)(n0 + r) * 384 + k0 + c4);
#pragma unroll
      for (int j = 0; j < 4; j++) lA[r][c4 + j] = f2bf(v[j]);
    }
    // stage W: 64 k-rows x 96 cols (k|v of head h), transposed (f32 -> bf16)
#pragma unroll
    for (int i = 0; i < 6; i++) {
      int idx = tid + (i << 8);               // 0..1535
      int r = idx / 24, g = idx % 24;
      int colbase = (g < 12) ? (384 + h * 48 + (g << 2)) : (768 + h * 48 + ((g - 12) << 2));
      f4 v = *(const f4*)(wqkv + (size_t)(k0 + r) * 1152 + colbase);
      int cb = g << 2;
#pragma unroll
      for (int j = 0; j < 4; j++) lW[cb + j][r] = f2bf(v[j]);
    }
    __syncthreads();
#pragma unroll
    for (int rt4 = 0; rt4 < 4; rt4++) {
      int m = (wv << 6) + (rt4 << 4) + l15;
#pragma unroll
      for (int kk = 0; kk < 2; kk++) {
        short8 af = *(const short8*)&lA[m][(kk << 5) + (quad << 3)];
#pragma unroll
        for (int ct = 0; ct < 6; ct++) {
          short8 bf = *(const short8*)&lW[(ct << 4) + l15][(kk << 5) + (quad << 3)];
          acc[rt4 * 6 + ct] = __builtin_amdgcn_mfma_f32_16x16x32_bf16(af, bf, acc[rt4 * 6 + ct], 0, 0, 0);
        }
      }
    }
  }
  __syncthreads();   // done reading lA/lW; smem reused as lk/lv
#pragma unroll
  for (int rt4 = 0; rt4 < 4; rt4++) {
#pragma unroll
    for (int ct = 0; ct < 6; ct++) {
      int col = (ct << 4) + l15;
#pragma unroll
      for (int rr = 0; rr < 4; rr++) {
        int row = (wv << 6) + (rt4 << 4) + (quad << 2) + rr;
        u16 val = f2bf(acc[rt4 * 6 + ct][rr]);
        if (col < 48) lk[row][col] = val; else lv[row][col - 48] = val;
      }
    }
  }
  __syncthreads();
  // softmax over each k row (thread tid owns row tid)
  {
    float v[48];
#pragma unroll
    for (int i = 0; i < 48; i++) v[i] = bf2f(lk[tid][i]);
    float m = v[0];
#pragma unroll
    for (int i = 1; i < 48; i++) m = fmaxf(m, v[i]);
    float s = 0.f;
#pragma unroll
    for (int i = 0; i < 48; i++) { v[i] = expf(v[i] - m); s += v[i]; }
    float inv = 1.0f / s;
#pragma unroll
    for (int i = 0; i < 48; i++) lk[tid][i] = f2bf(v[i] * inv);
  }
  __syncthreads();
  // ctx accumulation: each thread owns 9 (d,e) cells
  float a9[9]; int dd[9], ee[9];
#pragma unroll
  for (int i = 0; i < 9; i++) {
    int cell = tid + (i << 8);
    dd[i] = cell / 48; ee[i] = cell - dd[i] * 48; a9[i] = 0.f;
  }
  for (int r = 0; r < 256; r++) {
#pragma unroll
    for (int i = 0; i < 9; i++) a9[i] += bf2f(lk[r][dd[i]]) * bf2f(lv[r][ee[i]]);
  }
#pragma unroll
  for (int i = 0; i < 9; i++) atomicAdd(&ctx[(size_t)bh * 2304 + tid + (i << 8)], a9[i]);
}

// ---------------- Kernel 3: q GEMM tile + column sums of exp(q) -> S[b*384+col] -----------------
__global__ __launch_bounds__(256) void k_qsumk(
    const float* __restrict__ xa, const float* __restrict__ wqkv, float* __restrict__ S)
{
  const int bm = blockIdx.x;           // 512 row-tiles of 64
  const int b = bm >> 6;
  const int tid = threadIdx.x;
  const int wv = tid >> 6, lane = tid & 63, l15 = lane & 15, quad = lane >> 4;
  __shared__ __attribute__((aligned(16))) u16 lA[64][72];
  __shared__ __attribute__((aligned(16))) u16 lB[64][72];

  floatx4 acc[24];
  const floatx4 z = {0.f, 0.f, 0.f, 0.f};
#pragma unroll
  for (int i = 0; i < 24; i++) acc[i] = z;

  for (int k0 = 0; k0 < 384; k0 += 64) {
    __syncthreads();
#pragma unroll
    for (int i = 0; i < 4; i++) {
      int idx = tid + (i << 8);               // 0..1023
      int r = idx >> 4, c4 = (idx & 15) << 2;
      f4 v = *(const f4*)(xa + (size_t)((bm << 6) + r) * 384 + k0 + c4);
#pragma unroll
      for (int j = 0; j < 4; j++) lA[r][c4 + j] = f2bf(v[j]);
    }
    for (int ctg = 0; ctg < 6; ctg++) {
      __syncthreads();
#pragma unroll
      for (int i = 0; i < 4; i++) {
        int idx = tid + (i << 8);
        int r = idx >> 4, c4 = (idx & 15) << 2;    // r = k row, c4 = col offset
        f4 v = *(const f4*)(wqkv + (size_t)(k0 + r) * 1152 + (ctg << 6) + c4);
#pragma unroll
        for (int j = 0; j < 4; j++) lB[c4 + j][r] = f2bf(v[j]);
      }
      __syncthreads();
      int m = (wv << 4) + l15;
#pragma unroll
      for (int kk = 0; kk < 2; kk++) {
        short8 af = *(const short8*)&lA[m][(kk << 5) + (quad << 3)];
#pragma unroll
        for (int c4i = 0; c4i < 4; c4i++) {
          short8 bf = *(const short8*)&lB[(c4i << 4) + l15][(kk << 5) + (quad << 3)];
          acc[(ctg << 2) + c4i] = __builtin_amdgcn_mfma_f32_16x16x32_bf16(af, bf, acc[(ctg << 2) + c4i], 0, 0, 0);
        }
      }
    }
  }
#pragma unroll
  for (int t = 0; t < 24; t++) {
    float s = expf(acc[t][0]) + expf(acc[t][1]) + expf(acc[t][2]) + expf(acc[t][3]);
    s += __shfl_down(s, 32);
    s += __shfl_down(s, 16);
    if (lane < 16) atomicAdd(&S[b * 384 + (t << 4) + lane], s);
  }
}

// ---------------- Kernel 4: W2[b, h*48+d, c] = sum_e (ctx[bh,d,e]/S[..]) * wp[h*48+e, c] --------
// grid (64 bh, 3 coltiles of 128), block 256. LDS-staged, fully parallel.
__global__ __launch_bounds__(256) void k_w2(
    const float* __restrict__ ctx, const float* __restrict__ S,
    const float* __restrict__ wp, u16* __restrict__ W2)
{
  const int bh = blockIdx.x;   // 64
  const int b = bh >> 3, h = bh & 7;
  const int c0 = blockIdx.y << 7;
  const int tid = threadIdx.x;
  __shared__ float rs[48];
  __shared__ float c2[48][48];
  __shared__ float lwp[48][128];
  if (tid < 48) rs[tid] = 1.0f / S[b * 384 + h * 48 + tid];
  __syncthreads();
#pragma unroll
  for (int i = 0; i < 9; i++) {
    int cell = tid + (i << 8);
    int d = cell / 48, e = cell - d * 48;
    c2[d][e] = ctx[(size_t)bh * 2304 + cell] * rs[d];
  }
#pragma unroll
  for (int i = 0; i < 24; i++) {
    int idx = tid + (i << 8);            // 0..6143
    int e = idx >> 7, c = idx & 127;
    lwp[e][c] = wp[(size_t)(h * 48 + e) * 384 + c0 + c];
  }
  __syncthreads();
  const int c = tid & 127;
  const int dbase = tid >> 7;            // 0 or 1
#pragma unroll
  for (int it = 0; it < 24; it++) {
    int d = (it << 1) + dbase;
    float s = 0.f;
#pragma unroll
    for (int e = 0; e < 48; e++) s += c2[d][e] * lwp[e][c];
    W2[((size_t)b * 384 + h * 48 + d) * 384 + c0 + c] = f2bf(s);
  }
}

// ---------------- Kernel 5: out = exp(q_tile) @ W2_b + bias + x  (q recomputed in-block) --------
__global__ __launch_bounds__(256) void k_qproj(
    const float* __restrict__ xa, const float* __restrict__ wqkv, const u16* __restrict__ W2,
    const float* __restrict__ bias, const float* __restrict__ x, float* __restrict__ out)
{
  const int bm = blockIdx.x;           // 512 row-tiles of 64
  const int b = bm >> 6;
  const int tid = threadIdx.x;
  const int wv = tid >> 6, lane = tid & 63, l15 = lane & 15, quad = lane >> 4;
  __shared__ __attribute__((aligned(16))) u16 lA[64][72];
  __shared__ __attribute__((aligned(16))) u16 lB[64][72];
  __shared__ __attribute__((aligned(16))) u16 P[64][392];

  floatx4 acc[24];
  const floatx4 z = {0.f, 0.f, 0.f, 0.f};
#pragma unroll
  for (int i = 0; i < 24; i++) acc[i] = z;

  // phase 1: q = xa_rows @ wqkv[:, 0:384]
  for (int k0 = 0; k0 < 384; k0 += 64) {
    __syncthreads();
#pragma unroll
    for (int i = 0; i < 4; i++) {
      int idx = tid + (i << 8);
      int r = idx >> 4, c4 = (idx & 15) << 2;
      f4 v = *(const f4*)(xa + (size_t)((bm << 6) + r) * 384 + k0 + c4);
#pragma unroll
      for (int j = 0; j < 4; j++) lA[r][c4 + j] = f2bf(v[j]);
    }
    for (int ctg = 0; ctg < 6; ctg++) {
      __syncthreads();
#pragma unroll
      for (int i = 0; i < 4; i++) {
        int idx = tid + (i << 8);
        int r = idx >> 4, c4 = (idx & 15) << 2;
        f4 v = *(const f4*)(wqkv + (size_t)(k0 + r) * 1152 + (ctg << 6) + c4);
#pragma unroll
        for (int j = 0; j < 4; j++) lB[c4 + j][r] = f2bf(v[j]);
      }
      __syncthreads();
      int m = (wv << 4) + l15;
#pragma unroll
      for (int kk = 0; kk < 2; kk++) {
        short8 af = *(const short8*)&lA[m][(kk << 5) + (quad << 3)];
#pragma unroll
        for (int c4i = 0; c4i < 4; c4i++) {
          short8 bf = *(const short8*)&lB[(c4i << 4) + l15][(kk << 5) + (quad << 3)];
          acc[(ctg << 2) + c4i] = __builtin_amdgcn_mfma_f32_16x16x32_bf16(af, bf, acc[(ctg << 2) + c4i], 0, 0, 0);
        }
      }
    }
  }
  __syncthreads();
  // P = exp(q) in bf16
#pragma unroll
  for (int t = 0; t < 24; t++) {
    int col = (t << 4) + l15;
#pragma unroll
    for (int rr = 0; rr < 4; rr++) {
      int row = (wv << 4) + (quad << 2) + rr;
      P[row][col] = f2bf(expf(acc[t][rr]));
    }
  }
#pragma unroll
  for (int i = 0; i < 24; i++) acc[i] = z;
  __syncthreads();

  // phase 2: out_tile = P @ W2_b
  for (int k0 = 0; k0 < 384; k0 += 64) {
    for (int ctg = 0; ctg < 6; ctg++) {
      __syncthreads();
#pragma unroll
      for (int i = 0; i < 2; i++) {
        int idx = tid + (i << 8);
        int r = idx >> 3, c8 = (idx & 7) << 3;
        u16x8 v = *(const u16x8*)(W2 + ((size_t)b * 384 + k0 + r) * 384 + (ctg << 6) + c8);
#pragma unroll
        for (int j = 0; j < 8; j++) lB[c8 + j][r] = v[j];
      }
      __syncthreads();
      int m = (wv << 4) + l15;
#pragma unroll
      for (int kk = 0; kk < 2; kk++) {
        short8 af = *(const short8*)&P[m][k0 + (kk << 5) + (quad << 3)];
#pragma unroll
        for (int c4i = 0; c4i < 4; c4i++) {
          short8 bf = *(const short8*)&lB[(c4i << 4) + l15][(kk << 5) + (quad << 3)];
          acc[(ctg << 2) + c4i] = __builtin_amdgcn_mfma_f32_16x16x32_bf16(af, bf, acc[(ctg << 2) + c4i], 0, 0, 0);
        }
      }
    }
  }
  // epilogue: + bias + x, write out (own rows only -> in-place over xa is safe)
#pragma unroll
  for (int t = 0; t < 24; t++) {
    int col = (t << 4) + l15;
#pragma unroll
    for (int rr = 0; rr < 4; rr++) {
      int row = (bm << 6) + (wv << 4) + (quad << 2) + rr;
      float v = acc[t][rr] + bias[col] + x[(size_t)row * 384 + col];
      out[(size_t)row * 384 + col] = v;
    }
  }
}

extern "C" void kernel_launch(void* const* d_in, const int* in_sizes, int n_in,
                              void* d_out, int out_size, void* d_ws, size_t ws_size,
                              hipStream_t stream)
{
  const float* x      = (const float*)d_in[0];
  const float* w_sr   = (const float*)d_in[1];
  const float* b_sr   = (const float*)d_in[2];
  const float* ln_g   = (const float*)d_in[3];
  const float* ln_b   = (const float*)d_in[4];
  const float* w_qkv  = (const float*)d_in[5];
  const float* w_proj = (const float*)d_in[6];
  const float* b_proj = (const float*)d_in[7];
  float* out = (float*)d_out;

  // ws layout — total 2,961,408 bytes (~2.96 MB):
  //   [0,      12288)   S   [8][384] f32   (column sums of exp(q))
  //   [12288,  602112)  ctx [64][48][48] f32
  //   [602112, 2961408) W2  [8][384][384] bf16
  float* S   = (float*)d_ws;
  float* ctx = (float*)((char*)d_ws + 12288);
  u16*   W2  = (u16*)((char*)d_ws + 602112);
  float* xa  = out;   // conv result (f32) lives in d_out until k_qproj overwrites it row-locally

  hipMemsetAsync(d_ws, 0, 602112, stream);   // zero S + ctx

  k_conv_ln_gelu<<<BB * NN, CC, 0, stream>>>(x, w_sr, b_sr, ln_g, ln_b, xa);
  k_kvctx<<<dim3(128, 8), 256, 0, stream>>>(xa, w_qkv, ctx);
  k_qsumk<<<512, 256, 0, stream>>>(xa, w_qkv, S);
  k_w2<<<dim3(64, 3), 256, 0, stream>>>(ctx, S, w_proj, W2);
  k_qproj<<<512, 256, 0, stream>>>(xa, w_qkv, W2, b_proj, x, out);
}